// Round 20
// baseline (96.577 us; speedup 1.0000x reference)
//
#include <hip/hip_runtime.h>

#define IN_CH 96
#define OUT_CH 384
#define THREADS 384
#define TILE 32    // rows staged per block-iteration (12 KB LDS)

typedef float f32x4 __attribute__((ext_vector_type(4)));

// R20 = R13 champion structure (LDS-staged x, nt stores, pinned stash,
// grid 1024) with the LAST untested knob: store width. 4 channels/thread ->
// one f32x4 nt store per row (16B/lane, wave = 1KB contiguous, HALF the
// store instructions of the f32x2 champion). The 52-float stash previously
// spilled (R9: VGPR=36 under launch_bounds(384,5) cap=102) — here the cap
// is raised to 128 via (384,4), which is free at grid 1024 (4 blocks/CU
// either way). VGPR_Count is the validity discriminator: ~100 = resident,
// <=45 = spilled (test invalid).
// LDS banks for 4ch mapping: lanes span <=16 distinct c0; bank = c0 mod 32
// -> worst 2-3-way conflicts on the DS pipe (m136: ~free, pipe has slack).
__global__ __launch_bounds__(THREADS, 4) void skel_linear_kernel(
    const float* __restrict__ x,
    const float* __restrict__ weight,
    const float* __restrict__ mask,
    const float* __restrict__ bias,
    float* __restrict__ out,
    int batch)
{
    const int t     = threadIdx.x;
    const int cg    = t % 96;          // channel group (4 channels)
    const int rl    = t / 96;          // 0..3
    const int chan  = cg * 4;
    const int joint = cg >> 2;
    const int jc    = (joint - 1 < 0) ? 0 : ((joint - 1 > 21) ? 21 : joint - 1);
    const int c0    = jc * 4;          // contiguous 12-col window [c0, c0+12)

    // Masked weights + bias (52 floats), pinned via opaque asm redefinition.
    float w[4][12];
    float b[4];
#pragma unroll
    for (int j = 0; j < 4; ++j) {
        const size_t row = (size_t)(chan + j) * IN_CH;
#pragma unroll
        for (int c = 0; c < 12; ++c)
            w[j][c] = weight[row + c0 + c] * mask[row + c0 + c];
        b[j] = bias[chan + j];
    }
#pragma unroll
    for (int j = 0; j < 4; ++j) {
#pragma unroll
        for (int c = 0; c < 12; ++c)
            asm volatile("" : "+v"(w[j][c]));
        asm volatile("" : "+v"(b[j]));
    }

    __shared__ float xs[TILE * IN_CH];   // 32*96*4 = 12 KB

    const int ntiles = batch / TILE;     // 8192
    for (int tile = blockIdx.x; tile < ntiles; tile += gridDim.x) {
        // Stage 32 rows: 768 dwordx4, 2 per thread, perfectly coalesced.
        const f32x4* src = reinterpret_cast<const f32x4*>(
            x + (size_t)tile * (TILE * IN_CH));
        __syncthreads();                 // previous tile's readers done
        *reinterpret_cast<f32x4*>(&xs[4 * t])             = src[t];
        *reinterpret_cast<f32x4*>(&xs[4 * (t + THREADS)]) = src[t + THREADS];
        __syncthreads();                 // tile staged

        float* outb = out + (size_t)tile * (TILE * OUT_CH) + chan;
#pragma unroll 4
        for (int k = 0; k < TILE / 4; ++k) {
            const int rloc = 4 * k + rl;
            const float* xr = &xs[rloc * IN_CH + c0];
            const f32x4 xa = *reinterpret_cast<const f32x4*>(xr);
            const f32x4 xb = *reinterpret_cast<const f32x4*>(xr + 4);
            const f32x4 xc = *reinterpret_cast<const f32x4*>(xr + 8);

            f32x4 o4;
#pragma unroll
            for (int j = 0; j < 4; ++j) {
                float acc = b[j];
                acc = fmaf(w[j][0],  xa.x, acc);
                acc = fmaf(w[j][1],  xa.y, acc);
                acc = fmaf(w[j][2],  xa.z, acc);
                acc = fmaf(w[j][3],  xa.w, acc);
                acc = fmaf(w[j][4],  xb.x, acc);
                acc = fmaf(w[j][5],  xb.y, acc);
                acc = fmaf(w[j][6],  xb.z, acc);
                acc = fmaf(w[j][7],  xb.w, acc);
                acc = fmaf(w[j][8],  xc.x, acc);
                acc = fmaf(w[j][9],  xc.y, acc);
                acc = fmaf(w[j][10], xc.z, acc);
                acc = fmaf(w[j][11], xc.w, acc);
                o4[j] = acc;
            }

            __builtin_nontemporal_store(o4,
                reinterpret_cast<f32x4*>(outb + (size_t)rloc * OUT_CH));
        }
    }
}

extern "C" void kernel_launch(void* const* d_in, const int* in_sizes, int n_in,
                              void* d_out, int out_size, void* d_ws, size_t ws_size,
                              hipStream_t stream) {
    const float* x      = (const float*)d_in[0];
    const float* weight = (const float*)d_in[1];
    const float* mask   = (const float*)d_in[2];
    const float* bias   = (const float*)d_in[3];
    float* out          = (float*)d_out;

    const int batch = in_sizes[0] / IN_CH;   // 262144
    // 8192 tiles / 1024 blocks = exactly 8 tiles/block, 4 blocks/CU,
    // 24 waves/CU, 48 KB LDS/CU — proven best residency (R13 vs R19).
    const int grid = 1024;

    skel_linear_kernel<<<grid, THREADS, 0, stream>>>(x, weight, mask, bias, out, batch);
}